// Round 1
// baseline (436.515 us; speedup 1.0000x reference)
//
#include <hip/hip_runtime.h>

// 3x3 median pool, stride 1, zero-pad 1, on (8,32,512,512) fp32.
// One wave (64 lanes) per 8-row strip of one 512x512 image.
// Lane i owns output columns 8i..8i+7. Rows slide vertically in registers.

#define S2(a, b) { float _t = fminf(a, b); b = fmaxf(a, b); a = _t; }

__device__ __forceinline__ float med3f(float a, float b, float c) {
    return fmaxf(fminf(a, b), fminf(fmaxf(a, b), c));
}
__device__ __forceinline__ float max3f(float a, float b, float c) {
    return fmaxf(fmaxf(a, b), c);
}
__device__ __forceinline__ float min3f(float a, float b, float c) {
    return fminf(fminf(a, b), c);
}

__device__ __forceinline__ void load_row8(const float* __restrict__ p, float r[8]) {
    float4 v0 = *(const float4*)(p);
    float4 v1 = *(const float4*)(p + 4);
    r[0] = v0.x; r[1] = v0.y; r[2] = v0.z; r[3] = v0.w;
    r[4] = v1.x; r[5] = v1.y; r[6] = v1.z; r[7] = v1.w;
}

__global__ __launch_bounds__(256) void median_pool3x3_kernel(
        const float* __restrict__ in, float* __restrict__ out) {
    constexpr int W = 512, H = 512;
    constexpr int ROWS_PER_STRIP = 8;

    const int lane = threadIdx.x & 63;
    const int wave_in_block = threadIdx.x >> 6;
    const int gwave = blockIdx.x * 4 + wave_in_block;   // 4 waves per block

    // gwave -> (image, strip). 64 strips per image (512/8), 256 images.
    const int img = gwave >> 6;
    const int y0 = (gwave & 63) * ROWS_PER_STRIP;

    const float* __restrict__ base = in + (size_t)img * H * W;
    float* __restrict__ obase = out + (size_t)img * H * W;
    const int x0 = lane * 8;

    float rp[8], rc[8], rn[8];

    // prev row (y0-1): zero-pad if y0 == 0 (wave-uniform branch)
    if (y0 == 0) {
        #pragma unroll
        for (int j = 0; j < 8; ++j) rp[j] = 0.0f;
    } else {
        load_row8(base + (size_t)(y0 - 1) * W + x0, rp);
    }
    // current row (y0)
    load_row8(base + (size_t)y0 * W + x0, rc);

    #pragma unroll
    for (int yy = 0; yy < ROWS_PER_STRIP; ++yy) {
        const int y = y0 + yy;

        // next row (y+1): zero-pad if y+1 == H (wave-uniform)
        if (y + 1 < H) {
            load_row8(base + (size_t)(y + 1) * W + x0, rn);
        } else {
            #pragma unroll
            for (int j = 0; j < 8; ++j) rn[j] = 0.0f;
        }

        // vertical sort3 for each owned column
        float lo[8], mi[8], hi[8];
        #pragma unroll
        for (int j = 0; j < 8; ++j) {
            float a = rp[j], b = rc[j], c = rn[j];
            S2(a, b); S2(b, c); S2(a, b);
            lo[j] = a; mi[j] = b; hi[j] = c;
        }

        // neighbor sorted columns via cross-lane shuffle of sorted triples
        float loL = __shfl_up(lo[7], 1);
        float miL = __shfl_up(mi[7], 1);
        float hiL = __shfl_up(hi[7], 1);
        float loR = __shfl_down(lo[0], 1);
        float miR = __shfl_down(mi[0], 1);
        float hiR = __shfl_down(hi[0], 1);
        if (lane == 0)  { loL = 0.0f; miL = 0.0f; hiL = 0.0f; }   // x = -1 pad
        if (lane == 63) { loR = 0.0f; miR = 0.0f; hiR = 0.0f; }   // x = 512 pad

        float o[8];
        o[0] = med3f(max3f(loL, lo[0], lo[1]),
                     med3f(miL, mi[0], mi[1]),
                     min3f(hiL, hi[0], hi[1]));
        #pragma unroll
        for (int j = 1; j < 7; ++j) {
            o[j] = med3f(max3f(lo[j-1], lo[j], lo[j+1]),
                         med3f(mi[j-1], mi[j], mi[j+1]),
                         min3f(hi[j-1], hi[j], hi[j+1]));
        }
        o[7] = med3f(max3f(lo[6], lo[7], loR),
                     med3f(mi[6], mi[7], miR),
                     min3f(hi[6], hi[7], hiR));

        float4* op = (float4*)(obase + (size_t)y * W + x0);
        op[0] = make_float4(o[0], o[1], o[2], o[3]);
        op[1] = make_float4(o[4], o[5], o[6], o[7]);

        // slide rows down
        #pragma unroll
        for (int j = 0; j < 8; ++j) { rp[j] = rc[j]; rc[j] = rn[j]; }
    }
}

extern "C" void kernel_launch(void* const* d_in, const int* in_sizes, int n_in,
                              void* d_out, int out_size, void* d_ws, size_t ws_size,
                              hipStream_t stream) {
    const float* x = (const float*)d_in[0];
    float* out = (float*)d_out;

    // 8*32 = 256 images, 64 strips each = 16384 waves; 4 waves/block -> 4096 blocks
    const int total_waves = 256 * 64;
    const int blocks = total_waves / 4;
    median_pool3x3_kernel<<<blocks, 256, 0, stream>>>(x, out);
}

// Round 2
// 429.991 us; speedup vs baseline: 1.0152x; 1.0152x over previous
//
#include <hip/hip_runtime.h>

// 3x3 median pool, stride 1, zero-pad 1, (8,32,512,512) fp32.
// One wave per (8-row x 256-col) strip: lane i owns 4 contiguous columns
// (float4 loads/stores, fully coalesced). All 10 input rows of the strip
// are loaded up-front for deep MLP. Wave-edge halo columns loaded by
// lanes 0/63 (1 dword each), which then own the neighbor sorted triple.

#define S2(a, b) { float _t = fminf(a, b); b = fmaxf(a, b); a = _t; }

__device__ __forceinline__ float med3f(float a, float b, float c) {
    return fmaxf(fminf(a, b), fminf(fmaxf(a, b), c));
}
__device__ __forceinline__ float max3f(float a, float b, float c) {
    return fmaxf(fmaxf(a, b), c);
}
__device__ __forceinline__ float min3f(float a, float b, float c) {
    return fminf(fminf(a, b), c);
}

__global__ __launch_bounds__(256, 4) void median_pool3x3_kernel(
        const float* __restrict__ in, float* __restrict__ out) {
    constexpr int W = 512, H = 512;
    constexpr int RPS = 8;                 // output rows per strip

    const int lane = threadIdx.x & 63;
    const int wib  = threadIdx.x >> 6;
    const int gw   = blockIdx.x * 4 + wib;

    // gw -> { img (256), strip (64), half (2) }
    const int half  = gw & 1;
    const int strip = (gw >> 1) & 63;
    const int img   = gw >> 7;

    const int x0w = half * 256;
    const int y0  = strip * RPS;
    const float* __restrict__ base  = in  + (size_t)img * H * W;
    float* __restrict__       obase = out + (size_t)img * H * W;
    const int x0 = x0w + lane * 4;

    // Halo column config: lane 0 owns column x0w-1, lane 63 owns x0w+256.
    const bool isL = (lane == 0), isR = (lane == 63);
    const int  hx = isL ? (x0w - 1) : (x0w + 256);
    const bool hActive = (isL && x0w > 0) || (isR && x0w + 256 < W);

    // ---- load all 10 rows (y0-1 .. y0+8) up front: max loads in flight ----
    float4 r[RPS + 2];
    float  h[RPS + 2];
    #pragma unroll
    for (int i = 0; i < RPS + 2; ++i) {
        const int y = y0 - 1 + i;
        h[i] = 0.0f;
        if (y >= 0 && y < H) {            // wave-uniform (strip edges only)
            r[i] = *(const float4*)(base + (size_t)y * W + x0);
            if (hActive) h[i] = base[(size_t)y * W + hx];
        } else {
            r[i] = make_float4(0.f, 0.f, 0.f, 0.f);
        }
    }

    // ---- compute 8 output rows ----
    #pragma unroll
    for (int yy = 0; yy < RPS; ++yy) {
        const int y = y0 + yy;

        float av[4] = { r[yy].x,   r[yy].y,   r[yy].z,   r[yy].w   };
        float bv[4] = { r[yy+1].x, r[yy+1].y, r[yy+1].z, r[yy+1].w };
        float cv[4] = { r[yy+2].x, r[yy+2].y, r[yy+2].z, r[yy+2].w };

        float lo[4], mi[4], hi[4];
        #pragma unroll
        for (int j = 0; j < 4; ++j) {
            float a = av[j], b = bv[j], c = cv[j];
            S2(a, b); S2(b, c); S2(a, b);
            lo[j] = a; mi[j] = b; hi[j] = c;
        }

        // halo sorted triple (meaningful on lanes 0 and 63; zeros elsewhere)
        float ha = h[yy], hb = h[yy+1], hc = h[yy+2];
        S2(ha, hb); S2(hb, hc); S2(ha, hb);

        // neighbor sorted columns from adjacent lanes
        float loL = __shfl_up(lo[3], 1);
        float miL = __shfl_up(mi[3], 1);
        float hiL = __shfl_up(hi[3], 1);
        float loR = __shfl_down(lo[0], 1);
        float miR = __shfl_down(mi[0], 1);
        float hiR = __shfl_down(hi[0], 1);
        if (isL) { loL = ha; miL = hb; hiL = hc; }
        if (isR) { loR = ha; miR = hb; hiR = hc; }

        float o0 = med3f(max3f(loL,  lo[0], lo[1]),
                         med3f(miL,  mi[0], mi[1]),
                         min3f(hiL,  hi[0], hi[1]));
        float o1 = med3f(max3f(lo[0], lo[1], lo[2]),
                         med3f(mi[0], mi[1], mi[2]),
                         min3f(hi[0], hi[1], hi[2]));
        float o2 = med3f(max3f(lo[1], lo[2], lo[3]),
                         med3f(mi[1], mi[2], mi[3]),
                         min3f(hi[1], hi[2], hi[3]));
        float o3 = med3f(max3f(lo[2], lo[3], loR),
                         med3f(mi[2], mi[3], miR),
                         min3f(hi[2], hi[3], hiR));

        *(float4*)(obase + (size_t)y * W + x0) = make_float4(o0, o1, o2, o3);
    }
}

extern "C" void kernel_launch(void* const* d_in, const int* in_sizes, int n_in,
                              void* d_out, int out_size, void* d_ws, size_t ws_size,
                              hipStream_t stream) {
    const float* x = (const float*)d_in[0];
    float* out = (float*)d_out;

    // 256 images x 64 strips x 2 halves = 32768 waves; 4 waves/block
    const int blocks = 32768 / 4;
    median_pool3x3_kernel<<<blocks, 256, 0, stream>>>(x, out);
}